// Round 2
// baseline (42085.413 us; speedup 1.0000x reference)
//
#include <hip/hip_runtime.h>
#include <hip/hip_cooperative_groups.h>

namespace cg = cooperative_groups;

#define B_   256
#define T_   512
#define D_   200
#define H_   320
#define L_   3
#define G3_  960
#define BH_  (B_*H_)
#define BTH_ (B_*T_*H_)

// phase-1 geometry: block = (layer, col-group of 12); covers all 256 rows
#define CPB  12
#define NCG  80              // 960/12
#define NBLK (L_*NCG)        // 240  (<= 256 so cooperative launch always fits)
#define NTHR 256
#define KT   20              // k-tile depth
#define WSTR 644             // padded weight LDS stride (floats); 644%32=4 -> conflict-free

__device__ __forceinline__ float sigmoidf_(float v) {
    return 1.0f / (1.0f + __expf(-v));
}

__device__ __forceinline__ float wredsum(float v) {
#pragma unroll
    for (int m = 32; m > 0; m >>= 1) v += __shfl_xor(v, m, 64);
    return v;
}

__device__ __forceinline__ void load_weights(int l, int colbase, int tid,
        const float* __restrict__ wih0, const float* __restrict__ wihr,
        const float* __restrict__ whh, float (*w)[WSTR])
{
    const int KIH = (l == 0) ? D_ : H_;
    if (l == 0) {
        for (int e = tid; e < CPB*D_; e += NTHR) {
            int c = e / D_, k = e % D_;
            w[c][k] = wih0[(colbase + c)*D_ + k];
        }
    } else {
        for (int e = tid; e < CPB*H_; e += NTHR) {
            int c = e / H_, k = e % H_;
            w[c][k] = wihr[((l-1)*G3_ + colbase + c)*H_ + k];
        }
    }
    for (int e = tid; e < CPB*H_; e += NTHR) {
        int c = e / H_, k = e % H_;
        w[c][KIH + k] = whh[(l*G3_ + colbase + c)*H_ + k];
    }
}

// SRC: 0 = normalized x (layer 0 input), 1 = state[l-1], 2 = state[l] (h2h)
template<int SRC>
__device__ __forceinline__ void gemm_part(int l, int t, int rowbase, int colg, int tid,
        int Klen, int wOff,
        const float* __restrict__ x, const float* __restrict__ rmean,
        const float* __restrict__ rvar, const float* __restrict__ state,
        const float (*w)[WSTR], float (*tileT)[256], float acc[4][3])
{
    const float* src = (SRC == 1) ? (state + (size_t)(l-1)*BH_)
                                  : (state + (size_t)l*BH_);
    for (int k0 = 0; k0 < Klen; k0 += KT) {
        // ---- stage KT x 256 tile, transposed: tileT[k][row] ----
#pragma unroll
        for (int p = 0; p < 5; ++p) {
            int e   = p*NTHR + tid;        // 0..1279
            int row = e / 5;
            int k4  = e % 5;
            int kg  = k0 + k4*4;
            float4 v;
            if (SRC == 0) {
                float4 xv = *(const float4*)&x[((size_t)row*T_ + t)*D_ + kg];
                float4 mv = *(const float4*)&rmean[kg];
                float4 vv = *(const float4*)&rvar[kg];
                v.x = fminf(fmaxf((xv.x - mv.x)*rsqrtf(vv.x + 1e-8f), -10.f), 10.f);
                v.y = fminf(fmaxf((xv.y - mv.y)*rsqrtf(vv.y + 1e-8f), -10.f), 10.f);
                v.z = fminf(fmaxf((xv.z - mv.z)*rsqrtf(vv.z + 1e-8f), -10.f), 10.f);
                v.w = fminf(fmaxf((xv.w - mv.w)*rsqrtf(vv.w + 1e-8f), -10.f), 10.f);
            } else {
                v = *(const float4*)&src[(size_t)row*H_ + kg];
            }
            tileT[k4*4+0][row] = v.x;
            tileT[k4*4+1][row] = v.y;
            tileT[k4*4+2][row] = v.z;
            tileT[k4*4+3][row] = v.w;
        }
        __syncthreads();
        // ---- compute: 4 rows x 3 cols per thread ----
#pragma unroll
        for (int k4 = 0; k4 < 5; ++k4) {
            float4 i0 = *(const float4*)&tileT[k4*4+0][rowbase];
            float4 i1 = *(const float4*)&tileT[k4*4+1][rowbase];
            float4 i2 = *(const float4*)&tileT[k4*4+2][rowbase];
            float4 i3 = *(const float4*)&tileT[k4*4+3][rowbase];
#pragma unroll
            for (int j = 0; j < 3; ++j) {
                float4 wv = *(const float4*)&w[colg*3 + j][wOff + k0 + k4*4];
                acc[0][j] += i0.x*wv.x + i1.x*wv.y + i2.x*wv.z + i3.x*wv.w;
                acc[1][j] += i0.y*wv.x + i1.y*wv.y + i2.y*wv.z + i3.y*wv.w;
                acc[2][j] += i0.z*wv.x + i1.z*wv.y + i2.z*wv.z + i3.z*wv.w;
                acc[3][j] += i0.w*wv.x + i1.w*wv.y + i2.w*wv.z + i3.w*wv.w;
            }
        }
        __syncthreads();
    }
}

__device__ __forceinline__ void phase1_work(int l, int t, int colbase, int tid,
        const float* __restrict__ x, const float* __restrict__ rmean,
        const float* __restrict__ rvar, const float* __restrict__ bih,
        const float* __restrict__ bhh, float* __restrict__ state,
        float* __restrict__ zbuf, float* __restrict__ hnbuf,
        const float (*w)[WSTR], float (*tileT)[256])
{
    const int rowg = tid >> 2, colg = tid & 3;
    const int rowbase = rowg * 4;
    float accI[4][3] = {};
    float accH[4][3] = {};
    const int KIH = (l == 0) ? D_ : H_;
    if (l == 0) gemm_part<0>(l, t, rowbase, colg, tid, D_, 0,   x, rmean, rvar, state, w, tileT, accI);
    else        gemm_part<1>(l, t, rowbase, colg, tid, H_, 0,   x, rmean, rvar, state, w, tileT, accI);
    gemm_part<2>(l, t, rowbase, colg, tid, H_, KIH, x, rmean, rvar, state, w, tileT, accH);

#pragma unroll
    for (int j = 0; j < 3; ++j) {
        const int col = colbase + colg*3 + j;
        const float bi = bih[l*G3_ + col];
        const float bh = bhh[l*G3_ + col];
#pragma unroll
        for (int i = 0; i < 4; ++i) {
            const int row = rowbase + i;
            float gi = accI[i][j] + bi;
            float gh = accH[i][j] + bh;
            if (col < 2*H_) {
                zbuf[((size_t)l*B_ + row)*G3_ + col] = gi + gh;
            } else {
                zbuf[((size_t)l*B_ + row)*G3_ + col] = gi;
                hnbuf[((size_t)l*B_ + row)*H_ + (col - 2*H_)] = gh;
            }
        }
    }
}

__device__ __forceinline__ void phase2_work(int tau, int gtid,
        const float* __restrict__ lng, const float* __restrict__ lnb,
        float* __restrict__ state, const float* __restrict__ zbuf,
        const float* __restrict__ hnbuf, float* __restrict__ out)
{
    const int gw   = gtid >> 6;
    const int lane = gtid & 63;
    if (gw < L_*B_) {
        const int l2 = gw >> 8;
        const int b2 = gw & 255;
        const int t2 = tau - l2;
        if (t2 >= 0 && t2 < T_) {
            const float* zrow  = &zbuf[((size_t)l2*B_ + b2)*G3_];
            const float* hnrow = &hnbuf[((size_t)l2*B_ + b2)*H_];
            float*       hrow  = &state[(size_t)l2*BH_ + b2*H_];

            float zr[5], zu[5], zn[5], hn[5];
#pragma unroll
            for (int i = 0; i < 5; ++i) {
                const int j = lane + i*64;
                zr[i] = zrow[j];
                zu[i] = zrow[320 + j];
                zn[i] = zrow[640 + j];
                hn[i] = hnrow[j];
            }
            const float inv320 = 1.0f/320.0f;
            // LN(r)
            float s = zr[0]+zr[1]+zr[2]+zr[3]+zr[4];
            float mu = wredsum(s) * inv320;
            float vs = 0.f;
#pragma unroll
            for (int i = 0; i < 5; ++i) { float d = zr[i]-mu; vs += d*d; }
            float inv = rsqrtf(wredsum(vs)*inv320 + 1e-5f);
            float r[5];
#pragma unroll
            for (int i = 0; i < 5; ++i) {
                const int j = lane + i*64;
                r[i] = sigmoidf_((zr[i]-mu)*inv * lng[(l2*3+0)*H_ + j] + lnb[(l2*3+0)*H_ + j]);
            }
            // LN(u)
            s = zu[0]+zu[1]+zu[2]+zu[3]+zu[4];
            mu = wredsum(s) * inv320;
            vs = 0.f;
#pragma unroll
            for (int i = 0; i < 5; ++i) { float d = zu[i]-mu; vs += d*d; }
            inv = rsqrtf(wredsum(vs)*inv320 + 1e-5f);
            float u[5];
#pragma unroll
            for (int i = 0; i < 5; ++i) {
                const int j = lane + i*64;
                u[i] = sigmoidf_((zu[i]-mu)*inv * lng[(l2*3+1)*H_ + j] + lnb[(l2*3+1)*H_ + j]);
            }
            // n = tanh(LN(gi_n + r*hn))
            float z2[5];
#pragma unroll
            for (int i = 0; i < 5; ++i) z2[i] = zn[i] + r[i]*hn[i];
            s = z2[0]+z2[1]+z2[2]+z2[3]+z2[4];
            mu = wredsum(s) * inv320;
            vs = 0.f;
#pragma unroll
            for (int i = 0; i < 5; ++i) { float d = z2[i]-mu; vs += d*d; }
            inv = rsqrtf(wredsum(vs)*inv320 + 1e-5f);
#pragma unroll
            for (int i = 0; i < 5; ++i) {
                const int j = lane + i*64;
                float nv = tanhf((z2[i]-mu)*inv * lng[(l2*3+2)*H_ + j] + lnb[(l2*3+2)*H_ + j]);
                float hp = hrow[j];
                float hv = (1.0f - u[i])*nv + u[i]*hp;
                hrow[j] = hv;
                if (l2 == 2)    out[((size_t)b2*T_ + t2)*H_ + j] = hv;
                if (t2 == T_-1) out[(size_t)BTH_ + ((size_t)l2*B_ + b2)*H_ + j] = hv;
            }
        }
    }
}

// ======================= cooperative persistent kernel =======================
__launch_bounds__(NTHR)
__global__ void gru_coop_kernel(const float* __restrict__ x,
                                const float* __restrict__ h0,
                                const float* __restrict__ rmean,
                                const float* __restrict__ rvar,
                                const float* __restrict__ wih0,
                                const float* __restrict__ wihr,
                                const float* __restrict__ whh,
                                const float* __restrict__ bih,
                                const float* __restrict__ bhh,
                                const float* __restrict__ lng,
                                const float* __restrict__ lnb,
                                float* __restrict__ out,
                                float* __restrict__ ws)
{
    cg::grid_group grid = cg::this_grid();

    float* state = ws;
    float* zbuf  = ws + 3*BH_;
    float* hnbuf = ws + 3*BH_ + 3*B_*G3_;

    const int tid = threadIdx.x;
    const int bid = blockIdx.x;
    const int l   = bid / NCG;
    const int cg_ = bid % NCG;
    const int colbase = cg_ * CPB;

    __shared__ float w_lds[CPB][WSTR];   // 30912 B
    __shared__ float tileT[KT][256];     // 20480 B

    load_weights(l, colbase, tid, wih0, wihr, whh, w_lds);
    for (int idx = bid*NTHR + tid; idx < L_*BH_; idx += NBLK*NTHR)
        state[idx] = h0[idx];
    grid.sync();

    for (int tau = 0; tau < T_ + L_ - 1; ++tau) {
        const int t = tau - l;
        if (t >= 0 && t < T_)
            phase1_work(l, t, colbase, tid, x, rmean, rvar, bih, bhh,
                        state, zbuf, hnbuf, w_lds, tileT);
        grid.sync();
        phase2_work(tau, bid*NTHR + tid, lng, lnb, state, zbuf, hnbuf, out);
        grid.sync();
    }
}

// ======================= non-cooperative fallback path =======================
__global__ void k_init(const float* __restrict__ h0, float* __restrict__ state) {
    for (int i = blockIdx.x*blockDim.x + threadIdx.x; i < L_*BH_;
         i += gridDim.x*blockDim.x)
        state[i] = h0[i];
}

__launch_bounds__(NTHR)
__global__ void k_p1(const float* __restrict__ x,
                     const float* __restrict__ rmean,
                     const float* __restrict__ rvar,
                     const float* __restrict__ wih0,
                     const float* __restrict__ wihr,
                     const float* __restrict__ whh,
                     const float* __restrict__ bih,
                     const float* __restrict__ bhh,
                     float* __restrict__ ws, int tau)
{
    const int tid = threadIdx.x;
    const int bid = blockIdx.x;
    const int l   = bid / NCG;
    const int cg_ = bid % NCG;
    const int colbase = cg_ * CPB;
    const int t = tau - l;
    if (t < 0 || t >= T_) return;     // block-uniform

    float* state = ws;
    float* zbuf  = ws + 3*BH_;
    float* hnbuf = ws + 3*BH_ + 3*B_*G3_;

    __shared__ float w_lds[CPB][WSTR];
    __shared__ float tileT[KT][256];
    load_weights(l, colbase, tid, wih0, wihr, whh, w_lds);
    __syncthreads();
    phase1_work(l, t, colbase, tid, x, rmean, rvar, bih, bhh,
                state, zbuf, hnbuf, w_lds, tileT);
}

__launch_bounds__(NTHR)
__global__ void k_p2(const float* __restrict__ lng,
                     const float* __restrict__ lnb,
                     float* __restrict__ ws, float* __restrict__ out, int tau)
{
    float* state = ws;
    float* zbuf  = ws + 3*BH_;
    float* hnbuf = ws + 3*BH_ + 3*B_*G3_;
    phase2_work(tau, blockIdx.x*NTHR + threadIdx.x, lng, lnb,
                state, zbuf, hnbuf, out);
}

extern "C" void kernel_launch(void* const* d_in, const int* in_sizes, int n_in,
                              void* d_out, int out_size, void* d_ws, size_t ws_size,
                              hipStream_t stream) {
    (void)in_sizes; (void)n_in; (void)out_size; (void)ws_size;
    const float* x     = (const float*)d_in[0];
    const float* h0    = (const float*)d_in[1];
    const float* rmean = (const float*)d_in[2];
    const float* rvar  = (const float*)d_in[3];
    const float* wih0  = (const float*)d_in[4];
    const float* wihr  = (const float*)d_in[5];
    const float* whh   = (const float*)d_in[6];
    const float* bih   = (const float*)d_in[7];
    const float* bhh   = (const float*)d_in[8];
    const float* lng   = (const float*)d_in[9];
    const float* lnb   = (const float*)d_in[10];
    float* out = (float*)d_out;
    float* ws  = (float*)d_ws;

    // Decide path WITHOUT attempting a launch that could fail (a failed launch
    // during graph capture would invalidate the capture).
    int ncu = 0, nb = 0;
    hipDeviceGetAttribute(&ncu, hipDeviceAttributeMultiprocessorCount, 0);
    hipError_t qerr = hipOccupancyMaxActiveBlocksPerMultiprocessor(
        &nb, (const void*)gru_coop_kernel, NTHR, 0);
    const bool coop_ok = (qerr == hipSuccess) && (nb > 0) &&
                         ((long long)nb * (long long)ncu >= NBLK);

    if (coop_ok) {
        void* args[13] = {
            (void*)&x, (void*)&h0, (void*)&rmean, (void*)&rvar,
            (void*)&wih0, (void*)&wihr, (void*)&whh,
            (void*)&bih, (void*)&bhh, (void*)&lng, (void*)&lnb,
            (void*)&out, (void*)&ws
        };
        hipLaunchCooperativeKernel((void*)gru_coop_kernel,
                                   dim3(NBLK), dim3(NTHR), args, 0, stream);
    } else {
        k_init<<<dim3(240), dim3(NTHR), 0, stream>>>(h0, ws);
        for (int tau = 0; tau < T_ + L_ - 1; ++tau) {
            k_p1<<<dim3(NBLK), dim3(NTHR), 0, stream>>>(
                x, rmean, rvar, wih0, wihr, whh, bih, bhh, ws, tau);
            k_p2<<<dim3(NBLK), dim3(NTHR), 0, stream>>>(lng, lnb, ws, out, tau);
        }
    }
}

// Round 3
// 32337.634 us; speedup vs baseline: 1.3014x; 1.3014x over previous
//
#include <hip/hip_runtime.h>
#include <hip/hip_fp16.h>

#define B_   256
#define T_   512
#define D_   200
#define H_   320
#define L_   3
#define G3_  960
#define BH_  (B_*H_)
#define BTH_ (B_*T_*H_)

#define GR_   4              // independent groups (batch split)
#define RPG_  64             // rows (batch) per group
#define CPB_  48             // output cols per block
#define NCG_  20             // col-groups per layer (960/48)
#define SPG_  60             // blocks per group (3 layers * 20)
#define NBLK  240
#define NTHR  256
#define KIP0  224            // layer-0 input K padded to 32-multiple
#define WSTR  648            // LDS weight row stride in f16 elems

typedef _Float16 half8 __attribute__((ext_vector_type(8)));
typedef float    f32x4 __attribute__((ext_vector_type(4)));

// ---- ws layout (floats) ----
#define OFF_STATE 0
#define SZ_STATE  (L_*BH_)                 // fp32 hidden state
#define OFF_Z     (OFF_STATE + SZ_STATE)
#define SZ_Z      (L_*B_*G3_)
#define OFF_HN    (OFF_Z + SZ_Z)
#define SZ_HN     (L_*B_*H_)
#define OFF_STF   (OFF_HN + SZ_HN)         // f16 hidden state copy (as 2-byte elems)
#define SZ_STF_F  ((L_*BH_)/2)             // float-equivalents
#define OFF_BAR   (OFF_STF + SZ_STF_F)     // barrier words (u32)
#define BAR_WORDS 256

__device__ __forceinline__ float sigmoidf_(float v) {
    return 1.0f / (1.0f + __expf(-v));
}

__device__ __forceinline__ float wredsum(float v) {
#pragma unroll
    for (int m = 32; m > 0; m >>= 1) v += __shfl_xor(v, m, 64);
    return v;
}

__device__ __forceinline__ half8 h8zero() {
    half8 a;
#pragma unroll
    for (int j = 0; j < 8; ++j) a[j] = (_Float16)0.f;
    return a;
}

// group barrier: one arrival atomic per block, epoch spin, agent scope
__device__ __forceinline__ void group_barrier(unsigned* cnt, unsigned* ep, int tid) {
    __syncthreads();
    if (tid == 0) {
        __threadfence();   // make this XCD's prior writes device-visible
        unsigned e = __hip_atomic_load(ep, __ATOMIC_RELAXED, __HIP_MEMORY_SCOPE_AGENT);
        unsigned old = __hip_atomic_fetch_add(cnt, 1u, __ATOMIC_ACQ_REL, __HIP_MEMORY_SCOPE_AGENT);
        if (old == (unsigned)(SPG_ - 1)) {
            __hip_atomic_store(cnt, 0u, __ATOMIC_RELAXED, __HIP_MEMORY_SCOPE_AGENT);
            __hip_atomic_fetch_add(ep, 1u, __ATOMIC_RELEASE, __HIP_MEMORY_SCOPE_AGENT);
        } else {
            while (__hip_atomic_load(ep, __ATOMIC_ACQUIRE, __HIP_MEMORY_SCOPE_AGENT) == e)
                __builtin_amdgcn_s_sleep(1);
        }
    }
    __syncthreads();
}

__device__ __forceinline__ void load_weights(int l, int colbase, int tid,
        const float* __restrict__ wih0, const float* __restrict__ wihr,
        const float* __restrict__ whh,  const float* __restrict__ rmean,
        const float* __restrict__ rvar,
        _Float16 (*w)[WSTR], float (*nrm)[KIP0])
{
    for (int e = tid; e < CPB_*WSTR; e += NTHR) ((_Float16*)w)[e] = (_Float16)0.f;
    if (l == 0) for (int e = tid; e < 2*KIP0; e += NTHR) ((float*)nrm)[e] = 0.f;
    __syncthreads();
    const int KI  = (l == 0) ? D_ : H_;
    const int KIP = (l == 0) ? KIP0 : H_;
    for (int e = tid; e < CPB_*KI; e += NTHR) {
        int c = e / KI, k = e - c*KI;
        float v = (l == 0) ? wih0[(size_t)(colbase + c)*D_ + k]
                           : wihr[((size_t)(l-1)*G3_ + colbase + c)*H_ + k];
        w[c][k] = (_Float16)v;
    }
    for (int e = tid; e < CPB_*H_; e += NTHR) {
        int c = e / H_, k = e - c*H_;
        w[c][KIP + k] = (_Float16)whh[((size_t)l*G3_ + colbase + c)*H_ + k];
    }
    if (l == 0) {
        for (int k = tid; k < D_; k += NTHR) {
            nrm[0][k] = rmean[k];
            nrm[1][k] = rsqrtf(rvar[k] + 1e-8f);
        }
    }
    __syncthreads();
}

template<int KTI, bool L0>
__device__ __forceinline__ void phase1_work(int g, int l, int t, int colbase, int tid,
        const float* __restrict__ x, const _Float16* __restrict__ stf,
        const float* __restrict__ bih, const float* __restrict__ bhh,
        float* __restrict__ zbuf, float* __restrict__ hnbuf,
        const _Float16 (*w)[WSTR], const float (*nrm)[KIP0])
{
    const int wid  = tid >> 6;
    const int lane = tid & 63;
    const int nr   = lane & 15;      // A-row within 16-tile / B-col within 16-tile
    const int grp  = lane >> 4;      // k-subgroup
    const int mb   = g*RPG_ + wid*16;
    constexpr int KIP = KTI * 32;

    f32x4 accI[3], accH[3];
#pragma unroll
    for (int nt = 0; nt < 3; ++nt) {
#pragma unroll
        for (int r = 0; r < 4; ++r) { accI[nt][r] = 0.f; accH[nt][r] = 0.f; }
    }

    // ---------- input-to-hidden ----------
#pragma unroll
    for (int kt = 0; kt < KTI; ++kt) {
        const int k0 = kt*32 + grp*8;
        half8 a;
        if (L0) {
            if (kt == KTI-1 && grp > 0) {
                a = h8zero();                    // k >= 200 zero pad
            } else {
                const float* xr = &x[((size_t)(mb + nr)*T_ + t)*D_ + k0];
                float xv[8];
                *(float4*)&xv[0] = *(const float4*)xr;
                *(float4*)&xv[4] = *(const float4*)(xr + 4);
#pragma unroll
                for (int j = 0; j < 8; ++j) {
                    float nv = (xv[j] - nrm[0][k0+j]) * nrm[1][k0+j];
                    a[j] = (_Float16)fminf(fmaxf(nv, -10.f), 10.f);
                }
            }
        } else {
            a = *(const half8*)&stf[(size_t)(l-1)*BH_ + (size_t)(mb + nr)*H_ + k0];
        }
#pragma unroll
        for (int nt = 0; nt < 3; ++nt) {
            half8 bf = *(const half8*)&w[nt*16 + nr][k0];
            accI[nt] = __builtin_amdgcn_mfma_f32_16x16x32_f16(a, bf, accI[nt], 0, 0, 0);
        }
    }
    // ---------- hidden-to-hidden (K = 320 always) ----------
#pragma unroll
    for (int kt = 0; kt < 10; ++kt) {
        const int k0 = kt*32 + grp*8;
        half8 a = *(const half8*)&stf[(size_t)l*BH_ + (size_t)(mb + nr)*H_ + k0];
#pragma unroll
        for (int nt = 0; nt < 3; ++nt) {
            half8 bf = *(const half8*)&w[nt*16 + nr][KIP + k0];
            accH[nt] = __builtin_amdgcn_mfma_f32_16x16x32_f16(a, bf, accH[nt], 0, 0, 0);
        }
    }
    // ---------- store pre-activations ----------
#pragma unroll
    for (int nt = 0; nt < 3; ++nt) {
        const int col = colbase + nt*16 + nr;
        const float bi = bih[l*G3_ + col];
        const float bh = bhh[l*G3_ + col];
        const bool ru = (colbase + nt*16) < 2*H_;     // uniform per nt
#pragma unroll
        for (int r = 0; r < 4; ++r) {
            const int m = mb + grp*4 + r;             // D row = (lane>>4)*4 + reg
            const size_t zi = ((size_t)l*B_ + m)*G3_ + col;
            if (ru) {
                zbuf[zi] = accI[nt][r] + accH[nt][r] + bi + bh;
            } else {
                zbuf[zi] = accI[nt][r] + bi;
                hnbuf[((size_t)l*B_ + m)*H_ + (col - 2*H_)] = accH[nt][r] + bh;
            }
        }
    }
}

__device__ __forceinline__ void phase1_dispatch(int g, int l, int t, int colbase, int tid,
        const float* x, const _Float16* stf, const float* bih, const float* bhh,
        float* zbuf, float* hnbuf, const _Float16 (*w)[WSTR], const float (*nrm)[KIP0])
{
    if (l == 0) phase1_work<7,  true >(g, l, t, colbase, tid, x, stf, bih, bhh, zbuf, hnbuf, w, nrm);
    else        phase1_work<10, false>(g, l, t, colbase, tid, x, stf, bih, bhh, zbuf, hnbuf, w, nrm);
}

__device__ __forceinline__ void phase2_work(int g, int tau, int wv, int lane,
        const float* __restrict__ lng, const float* __restrict__ lnb,
        float* __restrict__ state, _Float16* __restrict__ stf,
        const float* __restrict__ zbuf, const float* __restrict__ hnbuf,
        float* __restrict__ out)
{
    const int l2 = wv >> 6;
    if (l2 >= L_) return;
    const int row = wv & 63;
    const int b2  = g*RPG_ + row;
    const int t2  = tau - l2;
    if (t2 < 0 || t2 >= T_) return;

    const float* zrow  = &zbuf[((size_t)l2*B_ + b2)*G3_];
    const float* hnrow = &hnbuf[((size_t)l2*B_ + b2)*H_];
    float*       hrow  = &state[(size_t)l2*BH_ + (size_t)b2*H_];
    _Float16*    frow  = &stf[(size_t)l2*BH_ + (size_t)b2*H_];

    float zr[5], zu[5], zn[5], hn[5];
#pragma unroll
    for (int i = 0; i < 5; ++i) {
        const int j = lane + i*64;
        zr[i] = zrow[j];
        zu[i] = zrow[320 + j];
        zn[i] = zrow[640 + j];
        hn[i] = hnrow[j];
    }
    const float inv320 = 1.0f/320.0f;
    // LN(r)
    float s  = zr[0]+zr[1]+zr[2]+zr[3]+zr[4];
    float mu = wredsum(s) * inv320;
    float vs = 0.f;
#pragma unroll
    for (int i = 0; i < 5; ++i) { float d = zr[i]-mu; vs += d*d; }
    float inv = rsqrtf(wredsum(vs)*inv320 + 1e-5f);
    float r[5];
#pragma unroll
    for (int i = 0; i < 5; ++i) {
        const int j = lane + i*64;
        r[i] = sigmoidf_((zr[i]-mu)*inv * lng[(l2*3+0)*H_ + j] + lnb[(l2*3+0)*H_ + j]);
    }
    // LN(u)
    s  = zu[0]+zu[1]+zu[2]+zu[3]+zu[4];
    mu = wredsum(s) * inv320;
    vs = 0.f;
#pragma unroll
    for (int i = 0; i < 5; ++i) { float d = zu[i]-mu; vs += d*d; }
    inv = rsqrtf(wredsum(vs)*inv320 + 1e-5f);
    float u[5];
#pragma unroll
    for (int i = 0; i < 5; ++i) {
        const int j = lane + i*64;
        u[i] = sigmoidf_((zu[i]-mu)*inv * lng[(l2*3+1)*H_ + j] + lnb[(l2*3+1)*H_ + j]);
    }
    // n = tanh(LN(gi_n + r*hn))
    float z2[5];
#pragma unroll
    for (int i = 0; i < 5; ++i) z2[i] = zn[i] + r[i]*hn[i];
    s  = z2[0]+z2[1]+z2[2]+z2[3]+z2[4];
    mu = wredsum(s) * inv320;
    vs = 0.f;
#pragma unroll
    for (int i = 0; i < 5; ++i) { float d = z2[i]-mu; vs += d*d; }
    inv = rsqrtf(wredsum(vs)*inv320 + 1e-5f);
#pragma unroll
    for (int i = 0; i < 5; ++i) {
        const int j = lane + i*64;
        float nv = tanhf((z2[i]-mu)*inv * lng[(l2*3+2)*H_ + j] + lnb[(l2*3+2)*H_ + j]);
        float hp = hrow[j];
        float hv = (1.0f - u[i])*nv + u[i]*hp;
        hrow[j] = hv;
        frow[j] = (_Float16)hv;
        if (l2 == 2)    out[((size_t)b2*T_ + t2)*H_ + j] = hv;
        if (t2 == T_-1) out[(size_t)BTH_ + ((size_t)l2*B_ + b2)*H_ + j] = hv;
    }
}

// ---- init: zero barrier words, copy h0 into fp32 + f16 state ----
__global__ void k_init(const float* __restrict__ h0, float* __restrict__ ws) {
    float*     state = ws + OFF_STATE;
    _Float16*  stf   = (_Float16*)(ws + OFF_STF);
    unsigned*  bar   = (unsigned*)(ws + OFF_BAR);
    int gt = blockIdx.x*blockDim.x + threadIdx.x;
    if (gt < BAR_WORDS) bar[gt] = 0u;
    for (int i = gt; i < L_*BH_; i += gridDim.x*blockDim.x) {
        float v = h0[i];
        state[i] = v;
        stf[i]   = (_Float16)v;
    }
}

// ======================= cooperative persistent kernel =======================
__launch_bounds__(NTHR)
__global__ void gru_coop_kernel(const float* __restrict__ x,
                                const float* __restrict__ h0,
                                const float* __restrict__ rmean,
                                const float* __restrict__ rvar,
                                const float* __restrict__ wih0,
                                const float* __restrict__ wihr,
                                const float* __restrict__ whh,
                                const float* __restrict__ bih,
                                const float* __restrict__ bhh,
                                const float* __restrict__ lng,
                                const float* __restrict__ lnb,
                                float* __restrict__ out,
                                float* __restrict__ ws)
{
    (void)h0;
    float*     state = ws + OFF_STATE;
    float*     zbuf  = ws + OFF_Z;
    float*     hnbuf = ws + OFF_HN;
    _Float16*  stf   = (_Float16*)(ws + OFF_STF);
    unsigned*  bar   = (unsigned*)(ws + OFF_BAR);

    const int tid = threadIdx.x;
    const int bid = blockIdx.x;
    const int g   = bid & (GR_ - 1);           // group: consecutive bids spread XCDs
    const int idx = bid >> 2;                  // 0..59 within group
    const int l   = idx / NCG_;
    const int cgp = idx - l*NCG_;
    const int colbase = cgp * CPB_;

    unsigned* cnt = &bar[g*64];
    unsigned* ep  = &bar[g*64 + 32];

    __shared__ _Float16 w_lds[CPB_][WSTR];     // 62208 B
    __shared__ float    nrm_lds[2][KIP0];      //  1792 B

    load_weights(l, colbase, tid, wih0, wihr, whh, rmean, rvar, w_lds, nrm_lds);

    const int wid  = tid >> 6;
    const int lane = tid & 63;

    for (int tau = 0; tau < T_ + L_ - 1; ++tau) {
        const int t = tau - l;
        if (t >= 0 && t < T_)
            phase1_dispatch(g, l, t, colbase, tid, x, stf, bih, bhh,
                            zbuf, hnbuf, w_lds, nrm_lds);
        group_barrier(cnt, ep, tid);
        phase2_work(g, tau, idx*4 + wid, lane, lng, lnb, state, stf, zbuf, hnbuf, out);
        group_barrier(cnt, ep, tid);
    }
}

// ======================= non-cooperative fallback path =======================
__launch_bounds__(NTHR)
__global__ void k_p1(const float* __restrict__ x,
                     const float* __restrict__ rmean, const float* __restrict__ rvar,
                     const float* __restrict__ wih0,  const float* __restrict__ wihr,
                     const float* __restrict__ whh,   const float* __restrict__ bih,
                     const float* __restrict__ bhh,   float* __restrict__ ws, int tau)
{
    const int tid = threadIdx.x;
    const int bid = blockIdx.x;
    const int g   = bid & (GR_ - 1);
    const int idx = bid >> 2;
    const int l   = idx / NCG_;
    const int cgp = idx - l*NCG_;
    const int colbase = cgp * CPB_;
    const int t = tau - l;
    if (t < 0 || t >= T_) return;

    float*    zbuf  = ws + OFF_Z;
    float*    hnbuf = ws + OFF_HN;
    _Float16* stf   = (_Float16*)(ws + OFF_STF);

    __shared__ _Float16 w_lds[CPB_][WSTR];
    __shared__ float    nrm_lds[2][KIP0];
    load_weights(l, colbase, tid, wih0, wihr, whh, rmean, rvar, w_lds, nrm_lds);
    phase1_dispatch(g, l, t, colbase, tid, x, stf, bih, bhh, zbuf, hnbuf, w_lds, nrm_lds);
}

__launch_bounds__(NTHR)
__global__ void k_p2(const float* __restrict__ lng, const float* __restrict__ lnb,
                     float* __restrict__ ws, float* __restrict__ out, int tau)
{
    float*    state = ws + OFF_STATE;
    float*    zbuf  = ws + OFF_Z;
    float*    hnbuf = ws + OFF_HN;
    _Float16* stf   = (_Float16*)(ws + OFF_STF);
    const int bid = blockIdx.x;
    const int g   = bid & (GR_ - 1);
    const int idx = bid >> 2;
    phase2_work(g, tau, idx*4 + (threadIdx.x >> 6), threadIdx.x & 63,
                lng, lnb, state, stf, zbuf, hnbuf, out);
}

extern "C" void kernel_launch(void* const* d_in, const int* in_sizes, int n_in,
                              void* d_out, int out_size, void* d_ws, size_t ws_size,
                              hipStream_t stream) {
    (void)in_sizes; (void)n_in; (void)out_size; (void)ws_size;
    const float* x     = (const float*)d_in[0];
    const float* h0    = (const float*)d_in[1];
    const float* rmean = (const float*)d_in[2];
    const float* rvar  = (const float*)d_in[3];
    const float* wih0  = (const float*)d_in[4];
    const float* wihr  = (const float*)d_in[5];
    const float* whh   = (const float*)d_in[6];
    const float* bih   = (const float*)d_in[7];
    const float* bhh   = (const float*)d_in[8];
    const float* lng   = (const float*)d_in[9];
    const float* lnb   = (const float*)d_in[10];
    float* out = (float*)d_out;
    float* ws  = (float*)d_ws;

    k_init<<<dim3(240), dim3(NTHR), 0, stream>>>(h0, ws);

    int ncu = 0, nb = 0;
    hipDeviceGetAttribute(&ncu, hipDeviceAttributeMultiprocessorCount, 0);
    hipError_t qerr = hipOccupancyMaxActiveBlocksPerMultiprocessor(
        &nb, (const void*)gru_coop_kernel, NTHR, 0);
    const bool coop_ok = (qerr == hipSuccess) && (nb > 0) &&
                         ((long long)nb * (long long)ncu >= NBLK);

    if (coop_ok) {
        void* args[13] = {
            (void*)&x, (void*)&h0, (void*)&rmean, (void*)&rvar,
            (void*)&wih0, (void*)&wihr, (void*)&whh,
            (void*)&bih, (void*)&bhh, (void*)&lng, (void*)&lnb,
            (void*)&out, (void*)&ws
        };
        hipLaunchCooperativeKernel((void*)gru_coop_kernel,
                                   dim3(NBLK), dim3(NTHR), args, 0, stream);
    } else {
        for (int tau = 0; tau < T_ + L_ - 1; ++tau) {
            k_p1<<<dim3(NBLK), dim3(NTHR), 0, stream>>>(
                x, rmean, rvar, wih0, wihr, whh, bih, bhh, ws, tau);
            k_p2<<<dim3(NBLK), dim3(NTHR), 0, stream>>>(lng, lnb, ws, out, tau);
        }
    }
}

// Round 4
// 22671.620 us; speedup vs baseline: 1.8563x; 1.4263x over previous
//
#include <hip/hip_runtime.h>
#include <hip/hip_fp16.h>

#define B_   256
#define T_   512
#define D_   200
#define H_   320
#define L_   3
#define G3_  960
#define BH_  (B_*H_)
#define BTH_ (B_*T_*H_)

#define GR_   8              // independent groups (batch split), one XCD each (hoped)
#define RPG_  32             // rows (batch) per group
#define CPB_  48             // output cols per block
#define NCG_  20             // col-groups per layer (960/48)
#define SPG_  60             // blocks per group (3 layers * 20)
#define NBLK  (GR_*SPG_)     // 480
#define NTHR  256
#define KIP0  224            // layer-0 input K padded to 32-multiple
#define WSTR  648            // LDS weight row stride in f16 elems

typedef _Float16 half8 __attribute__((ext_vector_type(8)));
typedef float    f32x4 __attribute__((ext_vector_type(4)));

// ---- ws layout (floats) ----
#define OFF_STATE 0
#define SZ_STATE  (L_*BH_)                 // fp32 hidden state
#define OFF_Z     (OFF_STATE + SZ_STATE)
#define SZ_Z      (L_*B_*G3_)
#define OFF_HN    (OFF_Z + SZ_Z)
#define SZ_HN     (L_*B_*H_)
#define OFF_STF   (OFF_HN + SZ_HN)         // f16 hidden state copy
#define SZ_STF_F  ((L_*BH_)/2)
#define OFF_BAR   (OFF_STF + SZ_STF_F)
#define GBAR_STRIDE 320                    // words per group's barrier region
#define EPOCH_W     256                    // epoch word offset inside region
#define BAR_WORDS   (GR_*GBAR_STRIDE)      // 2560

__device__ __forceinline__ float sigmoidf_(float v) {
    return 1.0f / (1.0f + __expf(-v));
}

__device__ __forceinline__ float wredsum(float v) {
#pragma unroll
    for (int m = 32; m > 0; m >>= 1) v += __shfl_xor(v, m, 64);
    return v;
}

__device__ __forceinline__ half8 h8zero() {
    half8 a;
#pragma unroll
    for (int j = 0; j < 8; ++j) a[j] = (_Float16)0.f;
    return a;
}

// ---- group barrier: single-writer flags + leader + RELAXED polls ----
// Arrival: release fence, then relaxed store of monotonic token to own flag.
// Leader (blk 0): wave0 lanes poll flags RELAXED until all >= token, then
// release-store epoch. Waiters: lane0 polls epoch RELAXED. One acquire fence
// per block at the end. No per-poll invalidates.
__device__ __forceinline__ void group_barrier(unsigned* gbar, int blk, int tid,
                                              unsigned token) {
    __syncthreads();
    if (tid < 64) {
        const int lane = tid;
        if (lane == 0) {
            __threadfence();   // release: push this block's stores to coherence point
            __hip_atomic_store(&gbar[blk*4], token, __ATOMIC_RELAXED,
                               __HIP_MEMORY_SCOPE_AGENT);
        }
        if (blk == 0) {
            for (;;) {
                unsigned v = token;
                if (lane < SPG_)
                    v = __hip_atomic_load(&gbar[lane*4], __ATOMIC_RELAXED,
                                          __HIP_MEMORY_SCOPE_AGENT);
                if (__all((int)(v - token) >= 0)) break;
                __builtin_amdgcn_s_sleep(2);
            }
            if (lane == 0)
                __hip_atomic_store(&gbar[EPOCH_W], token, __ATOMIC_RELEASE,
                                   __HIP_MEMORY_SCOPE_AGENT);
        } else if (lane == 0) {
            while ((int)(__hip_atomic_load(&gbar[EPOCH_W], __ATOMIC_RELAXED,
                                           __HIP_MEMORY_SCOPE_AGENT) - token) < 0)
                __builtin_amdgcn_s_sleep(2);
        }
        if (lane == 0) __threadfence();   // acquire: invalidate stale caches once
    }
    __syncthreads();
}

__device__ __forceinline__ void load_weights(int l, int colbase, int tid,
        const float* __restrict__ wih0, const float* __restrict__ wihr,
        const float* __restrict__ whh,  const float* __restrict__ rmean,
        const float* __restrict__ rvar,
        _Float16 (*w)[WSTR], float (*nrm)[KIP0])
{
    for (int e = tid; e < CPB_*WSTR; e += NTHR) ((_Float16*)w)[e] = (_Float16)0.f;
    if (l == 0) for (int e = tid; e < 2*KIP0; e += NTHR) ((float*)nrm)[e] = 0.f;
    __syncthreads();
    const int KI  = (l == 0) ? D_ : H_;
    const int KIP = (l == 0) ? KIP0 : H_;
    for (int e = tid; e < CPB_*KI; e += NTHR) {
        int c = e / KI, k = e - c*KI;
        float v = (l == 0) ? wih0[(size_t)(colbase + c)*D_ + k]
                           : wihr[((size_t)(l-1)*G3_ + colbase + c)*H_ + k];
        w[c][k] = (_Float16)v;
    }
    for (int e = tid; e < CPB_*H_; e += NTHR) {
        int c = e / H_, k = e - c*H_;
        w[c][KIP + k] = (_Float16)whh[((size_t)l*G3_ + colbase + c)*H_ + k];
    }
    if (l == 0) {
        for (int k = tid; k < D_; k += NTHR) {
            nrm[0][k] = rmean[k];
            nrm[1][k] = rsqrtf(rvar[k] + 1e-8f);
        }
    }
    __syncthreads();
}

template<int KTI, bool L0>
__device__ __forceinline__ void phase1_work(int g, int l, int t, int colbase, int tid,
        const float* __restrict__ x, const _Float16* __restrict__ stf,
        const float* __restrict__ bih, const float* __restrict__ bhh,
        float* __restrict__ zbuf, float* __restrict__ hnbuf,
        const _Float16 (*w)[WSTR], const float (*nrm)[KIP0])
{
    const int wid  = tid >> 6;       // 0 or 1 (callers gate wid<2)
    const int lane = tid & 63;
    const int nr   = lane & 15;
    const int grp  = lane >> 4;
    const int mb   = g*RPG_ + wid*16;
    constexpr int KIP = KTI * 32;

    f32x4 accI[3], accH[3];
#pragma unroll
    for (int nt = 0; nt < 3; ++nt) {
#pragma unroll
        for (int r = 0; r < 4; ++r) { accI[nt][r] = 0.f; accH[nt][r] = 0.f; }
    }

    // ---------- input-to-hidden ----------
#pragma unroll
    for (int kt = 0; kt < KTI; ++kt) {
        const int k0 = kt*32 + grp*8;
        half8 a;
        if (L0) {
            if (kt == KTI-1 && grp > 0) {
                a = h8zero();
            } else {
                const float* xr = &x[((size_t)(mb + nr)*T_ + t)*D_ + k0];
                float xv[8];
                *(float4*)&xv[0] = *(const float4*)xr;
                *(float4*)&xv[4] = *(const float4*)(xr + 4);
#pragma unroll
                for (int j = 0; j < 8; ++j) {
                    float nv = (xv[j] - nrm[0][k0+j]) * nrm[1][k0+j];
                    a[j] = (_Float16)fminf(fmaxf(nv, -10.f), 10.f);
                }
            }
        } else {
            a = *(const half8*)&stf[(size_t)(l-1)*BH_ + (size_t)(mb + nr)*H_ + k0];
        }
#pragma unroll
        for (int nt = 0; nt < 3; ++nt) {
            half8 bf = *(const half8*)&w[nt*16 + nr][k0];
            accI[nt] = __builtin_amdgcn_mfma_f32_16x16x32_f16(a, bf, accI[nt], 0, 0, 0);
        }
    }
    // ---------- hidden-to-hidden (K = 320) ----------
#pragma unroll
    for (int kt = 0; kt < 10; ++kt) {
        const int k0 = kt*32 + grp*8;
        half8 a = *(const half8*)&stf[(size_t)l*BH_ + (size_t)(mb + nr)*H_ + k0];
#pragma unroll
        for (int nt = 0; nt < 3; ++nt) {
            half8 bf = *(const half8*)&w[nt*16 + nr][KIP + k0];
            accH[nt] = __builtin_amdgcn_mfma_f32_16x16x32_f16(a, bf, accH[nt], 0, 0, 0);
        }
    }
    // ---------- store pre-activations ----------
#pragma unroll
    for (int nt = 0; nt < 3; ++nt) {
        const int col = colbase + nt*16 + nr;
        const float bi = bih[l*G3_ + col];
        const float bh = bhh[l*G3_ + col];
        const bool ru = (colbase + nt*16) < 2*H_;
#pragma unroll
        for (int r = 0; r < 4; ++r) {
            const int m = mb + grp*4 + r;
            const size_t zi = ((size_t)l*B_ + m)*G3_ + col;
            if (ru) {
                zbuf[zi] = accI[nt][r] + accH[nt][r] + bi + bh;
            } else {
                zbuf[zi] = accI[nt][r] + bi;
                hnbuf[((size_t)l*B_ + m)*H_ + (col - 2*H_)] = accH[nt][r] + bh;
            }
        }
    }
}

__device__ __forceinline__ void phase1_dispatch(int g, int l, int t, int colbase, int tid,
        const float* x, const _Float16* stf, const float* bih, const float* bhh,
        float* zbuf, float* hnbuf, const _Float16 (*w)[WSTR], const float (*nrm)[KIP0])
{
    if ((tid >> 6) >= 2) return;   // 2 waves of 16 rows cover RPG_=32
    if (l == 0) phase1_work<7,  true >(g, l, t, colbase, tid, x, stf, bih, bhh, zbuf, hnbuf, w, nrm);
    else        phase1_work<10, false>(g, l, t, colbase, tid, x, stf, bih, bhh, zbuf, hnbuf, w, nrm);
}

__device__ __forceinline__ void phase2_work(int g, int tau, int wv, int lane,
        const float* __restrict__ lng, const float* __restrict__ lnb,
        float* __restrict__ state, _Float16* __restrict__ stf,
        const float* __restrict__ zbuf, const float* __restrict__ hnbuf,
        float* __restrict__ out)
{
    if (wv >= L_*RPG_) return;            // 96 tasks per group
    const int l2  = wv >> 5;
    const int row = wv & 31;
    const int b2  = g*RPG_ + row;
    const int t2  = tau - l2;
    if (t2 < 0 || t2 >= T_) return;

    const float* zrow  = &zbuf[((size_t)l2*B_ + b2)*G3_];
    const float* hnrow = &hnbuf[((size_t)l2*B_ + b2)*H_];
    float*       hrow  = &state[(size_t)l2*BH_ + (size_t)b2*H_];
    _Float16*    frow  = &stf[(size_t)l2*BH_ + (size_t)b2*H_];

    float zr[5], zu[5], zn[5], hn[5];
#pragma unroll
    for (int i = 0; i < 5; ++i) {
        const int j = lane + i*64;
        zr[i] = zrow[j];
        zu[i] = zrow[320 + j];
        zn[i] = zrow[640 + j];
        hn[i] = hnrow[j];
    }
    const float inv320 = 1.0f/320.0f;
    float s  = zr[0]+zr[1]+zr[2]+zr[3]+zr[4];
    float mu = wredsum(s) * inv320;
    float vs = 0.f;
#pragma unroll
    for (int i = 0; i < 5; ++i) { float d = zr[i]-mu; vs += d*d; }
    float inv = rsqrtf(wredsum(vs)*inv320 + 1e-5f);
    float r[5];
#pragma unroll
    for (int i = 0; i < 5; ++i) {
        const int j = lane + i*64;
        r[i] = sigmoidf_((zr[i]-mu)*inv * lng[(l2*3+0)*H_ + j] + lnb[(l2*3+0)*H_ + j]);
    }
    s  = zu[0]+zu[1]+zu[2]+zu[3]+zu[4];
    mu = wredsum(s) * inv320;
    vs = 0.f;
#pragma unroll
    for (int i = 0; i < 5; ++i) { float d = zu[i]-mu; vs += d*d; }
    inv = rsqrtf(wredsum(vs)*inv320 + 1e-5f);
    float u[5];
#pragma unroll
    for (int i = 0; i < 5; ++i) {
        const int j = lane + i*64;
        u[i] = sigmoidf_((zu[i]-mu)*inv * lng[(l2*3+1)*H_ + j] + lnb[(l2*3+1)*H_ + j]);
    }
    float z2[5];
#pragma unroll
    for (int i = 0; i < 5; ++i) z2[i] = zn[i] + r[i]*hn[i];
    s  = z2[0]+z2[1]+z2[2]+z2[3]+z2[4];
    mu = wredsum(s) * inv320;
    vs = 0.f;
#pragma unroll
    for (int i = 0; i < 5; ++i) { float d = z2[i]-mu; vs += d*d; }
    inv = rsqrtf(wredsum(vs)*inv320 + 1e-5f);
#pragma unroll
    for (int i = 0; i < 5; ++i) {
        const int j = lane + i*64;
        float nv = tanhf((z2[i]-mu)*inv * lng[(l2*3+2)*H_ + j] + lnb[(l2*3+2)*H_ + j]);
        float hp = hrow[j];
        float hv = (1.0f - u[i])*nv + u[i]*hp;
        hrow[j] = hv;
        frow[j] = (_Float16)hv;
        if (l2 == 2)    out[((size_t)b2*T_ + t2)*H_ + j] = hv;
        if (t2 == T_-1) out[(size_t)BTH_ + ((size_t)l2*B_ + b2)*H_ + j] = hv;
    }
}

// ---- init: zero barrier words, copy h0 into fp32 + f16 state ----
__global__ void k_init(const float* __restrict__ h0, float* __restrict__ ws) {
    float*     state = ws + OFF_STATE;
    _Float16*  stf   = (_Float16*)(ws + OFF_STF);
    unsigned*  bar   = (unsigned*)(ws + OFF_BAR);
    int gt = blockIdx.x*blockDim.x + threadIdx.x;
    if (gt < BAR_WORDS) bar[gt] = 0u;
    for (int i = gt; i < L_*BH_; i += gridDim.x*blockDim.x) {
        float v = h0[i];
        state[i] = v;
        stf[i]   = (_Float16)v;
    }
}

// ======================= cooperative persistent kernel =======================
__launch_bounds__(NTHR)
__global__ void gru_coop_kernel(const float* __restrict__ x,
                                const float* __restrict__ h0,
                                const float* __restrict__ rmean,
                                const float* __restrict__ rvar,
                                const float* __restrict__ wih0,
                                const float* __restrict__ wihr,
                                const float* __restrict__ whh,
                                const float* __restrict__ bih,
                                const float* __restrict__ bhh,
                                const float* __restrict__ lng,
                                const float* __restrict__ lnb,
                                float* __restrict__ out,
                                float* __restrict__ ws)
{
    (void)h0;
    float*     state = ws + OFF_STATE;
    float*     zbuf  = ws + OFF_Z;
    float*     hnbuf = ws + OFF_HN;
    _Float16*  stf   = (_Float16*)(ws + OFF_STF);
    unsigned*  bar   = (unsigned*)(ws + OFF_BAR);

    const int tid = threadIdx.x;
    const int bid = blockIdx.x;
    const int g   = bid & (GR_ - 1);     // bid%8 -> (hopefully) per-XCD group
    const int idx = bid >> 3;            // 0..59 within group
    const int l   = idx / NCG_;
    const int cgp = idx - l*NCG_;
    const int colbase = cgp * CPB_;

    unsigned* gbar = bar + g*GBAR_STRIDE;

    __shared__ _Float16 w_lds[CPB_][WSTR];     // 62208 B
    __shared__ float    nrm_lds[2][KIP0];      //  1792 B

    load_weights(l, colbase, tid, wih0, wihr, whh, rmean, rvar, w_lds, nrm_lds);

    const int wid  = tid >> 6;
    const int lane = tid & 63;

    for (int tau = 0; tau < T_ + L_ - 1; ++tau) {
        const int t = tau - l;
        if (t >= 0 && t < T_)
            phase1_dispatch(g, l, t, colbase, tid, x, stf, bih, bhh,
                            zbuf, hnbuf, w_lds, nrm_lds);
        group_barrier(gbar, idx, tid, (unsigned)(2*tau + 1));
        phase2_work(g, tau, idx*4 + wid, lane, lng, lnb, state, stf, zbuf, hnbuf, out);
        group_barrier(gbar, idx, tid, (unsigned)(2*tau + 2));
    }
}

// ======================= non-cooperative fallback path =======================
__launch_bounds__(NTHR)
__global__ void k_p1(const float* __restrict__ x,
                     const float* __restrict__ rmean, const float* __restrict__ rvar,
                     const float* __restrict__ wih0,  const float* __restrict__ wihr,
                     const float* __restrict__ whh,   const float* __restrict__ bih,
                     const float* __restrict__ bhh,   float* __restrict__ ws, int tau)
{
    const int tid = threadIdx.x;
    const int bid = blockIdx.x;
    const int g   = bid & (GR_ - 1);
    const int idx = bid >> 3;
    const int l   = idx / NCG_;
    const int cgp = idx - l*NCG_;
    const int colbase = cgp * CPB_;
    const int t = tau - l;
    if (t < 0 || t >= T_) return;

    float*    zbuf  = ws + OFF_Z;
    float*    hnbuf = ws + OFF_HN;
    _Float16* stf   = (_Float16*)(ws + OFF_STF);

    __shared__ _Float16 w_lds[CPB_][WSTR];
    __shared__ float    nrm_lds[2][KIP0];
    load_weights(l, colbase, tid, wih0, wihr, whh, rmean, rvar, w_lds, nrm_lds);
    phase1_dispatch(g, l, t, colbase, tid, x, stf, bih, bhh, zbuf, hnbuf, w_lds, nrm_lds);
}

__launch_bounds__(NTHR)
__global__ void k_p2(const float* __restrict__ lng, const float* __restrict__ lnb,
                     float* __restrict__ ws, float* __restrict__ out, int tau)
{
    float*    state = ws + OFF_STATE;
    float*    zbuf  = ws + OFF_Z;
    float*    hnbuf = ws + OFF_HN;
    _Float16* stf   = (_Float16*)(ws + OFF_STF);
    const int bid = blockIdx.x;
    const int g   = bid & (GR_ - 1);
    const int idx = bid >> 3;
    phase2_work(g, tau, idx*4 + (threadIdx.x >> 6), threadIdx.x & 63,
                lng, lnb, state, stf, zbuf, hnbuf, out);
}

extern "C" void kernel_launch(void* const* d_in, const int* in_sizes, int n_in,
                              void* d_out, int out_size, void* d_ws, size_t ws_size,
                              hipStream_t stream) {
    (void)in_sizes; (void)n_in; (void)out_size; (void)ws_size;
    const float* x     = (const float*)d_in[0];
    const float* h0    = (const float*)d_in[1];
    const float* rmean = (const float*)d_in[2];
    const float* rvar  = (const float*)d_in[3];
    const float* wih0  = (const float*)d_in[4];
    const float* wihr  = (const float*)d_in[5];
    const float* whh   = (const float*)d_in[6];
    const float* bih   = (const float*)d_in[7];
    const float* bhh   = (const float*)d_in[8];
    const float* lng   = (const float*)d_in[9];
    const float* lnb   = (const float*)d_in[10];
    float* out = (float*)d_out;
    float* ws  = (float*)d_ws;

    k_init<<<dim3(240), dim3(NTHR), 0, stream>>>(h0, ws);

    int ncu = 0, nb = 0;
    hipDeviceGetAttribute(&ncu, hipDeviceAttributeMultiprocessorCount, 0);
    hipError_t qerr = hipOccupancyMaxActiveBlocksPerMultiprocessor(
        &nb, (const void*)gru_coop_kernel, NTHR, 0);
    const bool coop_ok = (qerr == hipSuccess) && (nb > 0) &&
                         ((long long)nb * (long long)ncu >= NBLK);

    if (coop_ok) {
        void* args[13] = {
            (void*)&x, (void*)&h0, (void*)&rmean, (void*)&rvar,
            (void*)&wih0, (void*)&wihr, (void*)&whh,
            (void*)&bih, (void*)&bhh, (void*)&lng, (void*)&lnb,
            (void*)&out, (void*)&ws
        };
        hipLaunchCooperativeKernel((void*)gru_coop_kernel,
                                   dim3(NBLK), dim3(NTHR), args, 0, stream);
    } else {
        for (int tau = 0; tau < T_ + L_ - 1; ++tau) {
            k_p1<<<dim3(NBLK), dim3(NTHR), 0, stream>>>(
                x, rmean, rvar, wih0, wihr, whh, bih, bhh, ws, tau);
            k_p2<<<dim3(NBLK), dim3(NTHR), 0, stream>>>(lng, lnb, ws, out, tau);
        }
    }
}